// Round 20
// baseline (69.540 us; speedup 1.0000x reference)
//
#include <hip/hip_runtime.h>
#include <stdint.h>

typedef __attribute__((ext_vector_type(8))) short s16x8;
typedef __attribute__((ext_vector_type(8))) unsigned short u16x8;
typedef __attribute__((ext_vector_type(4))) float f32x4;

#define D 512
#define BM 128
#define BK 64
#define CAP 96   // padded CSR row capacity; P(deg>=96) ~ 1e-40 for Binom(160000,1e-4)

__device__ __forceinline__ unsigned short f2bf(float f) {
    unsigned u = __float_as_uint(f);
    return (unsigned short)((u + 0x7FFFu + ((u >> 16) & 1u)) >> 16);
}
__device__ __forceinline__ float bf2f(unsigned short h) {
    return __uint_as_float(((unsigned)h) << 16);
}

// ---------------- fused launch 1: GEMM (0..315, dbuf, direct-W1 B-staging) +
//                  scatter (316..940) + w2l (941..1069) + out-init (1070) ----------------
__global__ __launch_bounds__(256) void k_gemm_scatter(const float* __restrict__ X,
                                                      const float* __restrict__ W1,
                                                      unsigned short* C, int Mreal,
                                                      const int* src, const int* dst,
                                                      int* fill, int* csr_src, int nE,
                                                      const float* W2, const float* Wlin,
                                                      const float* b2, const float* blin,
                                                      float* w2l, float* out, int nG) {
    __shared__ __align__(16) unsigned short smem[4 * BM * BK];   // As[2]+Bs[2]=64KB; epilogue reuses
    int b = blockIdx.x;
    int t = threadIdx.x;
    if (b >= 316) {
        int br = b - 316;
        if (br < 625) {                    // ---- scatter role: count + claim slot ----
            int e = br * 256 + t;
            if (e < nE) {
                int s = src[e], d = dst[e];
                int pos = atomicAdd(&fill[d], 1);
                if (pos < CAP) csr_src[(size_t)d * CAP + pos] = s;
            }
        } else if (br < 754) {             // ---- w2l role: one wave per row ----
            int i = (br - 625) * 4 + (t >> 6);
            int l = t & 63;
            if (i < D + 1) {
                const float* row = (i < D) ? (W2 + (size_t)i * D) : b2;
                float4 a0 = *(const float4*)(row + l * 8);
                float4 a1 = *(const float4*)(row + l * 8 + 4);
                float4 c0 = *(const float4*)(Wlin + l * 8);
                float4 c1 = *(const float4*)(Wlin + l * 8 + 4);
                float p = a0.x * c0.x + a0.y * c0.y + a0.z * c0.z + a0.w * c0.w
                        + a1.x * c1.x + a1.y * c1.y + a1.z * c1.z + a1.w * c1.w;
#pragma unroll
                for (int o = 32; o > 0; o >>= 1) p += __shfl_xor(p, o);
                if (l == 0) w2l[i] = p;
            }
        } else {                           // ---- out init ----
            if (t < nG) out[t] = blin[0];
        }
        return;
    }
    // ---- GEMM role: h1 = x @ W1; dbuf; B staged straight from f32 W1 (L2-resident) ----
    int tn0 = (b & 3) * BM, tm0 = (b >> 2) * BM;
    int lane = t & 63, wave = t >> 6;
    int wr = wave >> 1, wc = wave & 1;
    f32x4 acc[4][4] = {};
    int r15 = lane & 15;
    int khalf = lane >> 4;

    // A staging geometry: 4 × (row, 16B k-group)
    int a_row[4], a_kg[4];
    const float* a_gp_base[4];
#pragma unroll
    for (int i = 0; i < 4; ++i) {
        int idx = t + 256 * i;
        a_row[i] = idx >> 3; a_kg[i] = idx & 7;
        int grow = tm0 + a_row[i]; if (grow >= Mreal) grow = Mreal - 1;
        a_gp_base[i] = X + (size_t)grow * D + a_kg[i] * 8;
    }
    // B staging geometry: 4 × (n, k-group of 8); per-wave 256B-coalesced j-loads
    int b_n[4], b_kg[4];
#pragma unroll
    for (int p = 0; p < 4; ++p) {
        int idx = t + 256 * p;
        b_n[p] = idx & 127; b_kg[p] = idx >> 7;
    }

    float4 af0[4], af1[4];
    float bf[4][8];
    auto load_A = [&](int k0) {
#pragma unroll
        for (int i = 0; i < 4; ++i) {
            const float* gp = a_gp_base[i] + k0;
            af0[i] = *(const float4*)gp;
            af1[i] = *(const float4*)(gp + 4);
        }
    };
    auto load_B = [&](int k0) {
#pragma unroll
        for (int p = 0; p < 4; ++p) {
            const float* gp = W1 + (size_t)(k0 + b_kg[p] * 8) * D + tn0 + b_n[p];
#pragma unroll
            for (int j = 0; j < 8; ++j) bf[p][j] = gp[(size_t)j * D];
        }
    };
    auto write_A = [&](unsigned short* Asbuf) {
#pragma unroll
        for (int i = 0; i < 4; ++i) {
            u16x8 o;
            o[0] = f2bf(af0[i].x); o[1] = f2bf(af0[i].y); o[2] = f2bf(af0[i].z); o[3] = f2bf(af0[i].w);
            o[4] = f2bf(af1[i].x); o[5] = f2bf(af1[i].y); o[6] = f2bf(af1[i].z); o[7] = f2bf(af1[i].w);
            *(u16x8*)&Asbuf[a_row[i] * BK + (a_kg[i] ^ (a_row[i] & 7)) * 8] = o;
        }
    };
    auto write_B = [&](unsigned short* Bsbuf) {
#pragma unroll
        for (int p = 0; p < 4; ++p) {
            u16x8 o;
#pragma unroll
            for (int j = 0; j < 8; ++j) o[j] = f2bf(bf[p][j]);
            *(u16x8*)&Bsbuf[b_n[p] * BK + ((b_kg[p] ^ (b_n[p] & 7)) << 3)] = o;
        }
    };

    // prologue: fill buffer 0
    load_B(0);
    load_A(0);
    write_B(smem + 2 * BM * BK);
    write_A(smem);
    __syncthreads();

    int cur = 0;
    for (int k0 = 0; k0 < D; k0 += BK) {
        unsigned short* Asc = smem + cur * BM * BK;
        unsigned short* Bsc = smem + (2 + cur) * BM * BK;
        if (k0 + BK < D) {                 // issue next-step loads; latency hides under MFMA
            load_B(k0 + BK);
            load_A(k0 + BK);
        }
#pragma unroll
        for (int ks = 0; ks < 2; ++ks) {
            int g = ks * 4 + khalf;
            s16x8 a[4], bb[4];
#pragma unroll
            for (int m = 0; m < 4; ++m) {
                int row = wr * 64 + m * 16 + r15;
                a[m] = *(const s16x8*)&Asc[row * BK + (g ^ (row & 7)) * 8];
            }
#pragma unroll
            for (int n = 0; n < 4; ++n) {
                int row = wc * 64 + n * 16 + r15;
                bb[n] = *(const s16x8*)&Bsc[row * BK + (g ^ (row & 7)) * 8];
            }
#pragma unroll
            for (int m = 0; m < 4; ++m)
#pragma unroll
                for (int n = 0; n < 4; ++n)
                    acc[m][n] = __builtin_amdgcn_mfma_f32_16x16x32_bf16(a[m], bb[n], acc[m][n], 0, 0, 0);
        }
        if (k0 + BK < D) {
            write_B(smem + (2 + (cur ^ 1)) * BM * BK);
            write_A(smem + (cur ^ 1) * BM * BK);
        }
        __syncthreads();
        cur ^= 1;
    }

    // ---- epilogue: repack C-tile in LDS, coalesced 16B stores ----
    int cr = (lane >> 4) * 4;
    int cc = lane & 15;
#pragma unroll
    for (int m = 0; m < 4; ++m)
#pragma unroll
        for (int n = 0; n < 4; ++n)
#pragma unroll
            for (int r = 0; r < 4; ++r)
                smem[(wr * 64 + m * 16 + cr + r) * 132 + wc * 64 + n * 16 + cc] = f2bf(acc[m][n][r]);
    __syncthreads();
#pragma unroll
    for (int it = 0; it < 8; ++it) {
        int row = it * 16 + (t >> 4);
        int c8 = (t & 15) * 8;
        int grow = tm0 + row;
        if (grow < Mreal) {
            u16x8 vv = *(const u16x8*)&smem[row * 132 + c8];
            *(u16x8*)&C[(size_t)grow * D + tn0 + c8] = vv;
        }
    }
}

// ---------------- layer1 aggregate, feature-sliced + XCD-pinned, padded CSR (r13 exact) ----------------
__global__ __launch_bounds__(256) void k_agg1(const unsigned short* h1b, const int* csr_src,
                                              const int* fill, const float* b1,
                                              const float* w2l, float* z, int nN) {
    int bid = blockIdx.x;
    int xcd = bid & 7;
    int slice = xcd >> 1;
    int chunk = (bid >> 3) * 2 + (xcd & 1);   // node chunk of 16
    int t = threadIdx.x;
    int g = t >> 4;                 // group 0..15 in block
    int l = t & 15;                 // lane in group
    int v = chunk * 16 + g;
    if (v >= nN) return;
    int f0 = (slice << 7) + l * 8;

    float acc[8];
    float4 ba = *(const float4*)(b1 + f0);
    float4 bb = *(const float4*)(b1 + f0 + 4);
    acc[0] = ba.x; acc[1] = ba.y; acc[2] = ba.z; acc[3] = ba.w;
    acc[4] = bb.x; acc[5] = bb.y; acc[6] = bb.z; acc[7] = bb.w;

    int deg = fill[v];
    float degv1 = (float)(deg + 1);
    float wself = 1.0f / degv1;
    u16x8 hv = *(const u16x8*)(h1b + (size_t)v * D + f0);
#pragma unroll
    for (int j = 0; j < 8; ++j) acc[j] += wself * bf2f(hv[j]);

    const int* row = csr_src + (size_t)v * CAP;
    int sb = (g & 3) << 4;          // group's base lane within the wave
    for (int eb = 0; eb < deg; eb += 16) {
        int n = deg - eb; if (n > 16) n = 16;
        int myi = 0; float myw = 0.f;
        if (l < n) {
            myi = row[eb + l];
            myw = rsqrtf((float)(fill[myi] + 1) * degv1);
        }
        int j = 0;
        for (; j + 4 <= n; j += 4) {
            int s0 = __shfl(myi, sb + j),     s1 = __shfl(myi, sb + j + 1);
            int s2 = __shfl(myi, sb + j + 2), s3 = __shfl(myi, sb + j + 3);
            float w0 = __shfl(myw, sb + j),     w1 = __shfl(myw, sb + j + 1);
            float w2 = __shfl(myw, sb + j + 2), w3 = __shfl(myw, sb + j + 3);
            u16x8 h0 = *(const u16x8*)(h1b + (size_t)s0 * D + f0);
            u16x8 h1 = *(const u16x8*)(h1b + (size_t)s1 * D + f0);
            u16x8 h2 = *(const u16x8*)(h1b + (size_t)s2 * D + f0);
            u16x8 h3 = *(const u16x8*)(h1b + (size_t)s3 * D + f0);
#pragma unroll
            for (int q = 0; q < 8; ++q) acc[q] += w0 * bf2f(h0[q]);
#pragma unroll
            for (int q = 0; q < 8; ++q) acc[q] += w1 * bf2f(h1[q]);
#pragma unroll
            for (int q = 0; q < 8; ++q) acc[q] += w2 * bf2f(h2[q]);
#pragma unroll
            for (int q = 0; q < 8; ++q) acc[q] += w3 * bf2f(h3[q]);
        }
        for (; j < n; ++j) {
            int s = __shfl(myi, sb + j);
            float w = __shfl(myw, sb + j);
            u16x8 hs = *(const u16x8*)(h1b + (size_t)s * D + f0);
#pragma unroll
            for (int q = 0; q < 8; ++q) acc[q] += w * bf2f(hs[q]);
        }
    }

    float4 wa = *(const float4*)(w2l + f0);
    float4 wb = *(const float4*)(w2l + f0 + 4);
    float wv[8] = {wa.x, wa.y, wa.z, wa.w, wb.x, wb.y, wb.z, wb.w};
    float p = 0.f;
#pragma unroll
    for (int j = 0; j < 8; ++j) p += fmaxf(acc[j], 0.f) * wv[j];
    p += __shfl_xor(p, 8);
    p += __shfl_xor(p, 4);
    p += __shfl_xor(p, 2);
    p += __shfl_xor(p, 1);
    if (l == 0) atomicAdd(&z[v], p);
}

// ---------------- layer2 scalar aggregate + pool (edge-parallel, LDS bins) ----------------
__global__ __launch_bounds__(256) void k_agg2(const float* z, const int* src, const int* dst,
                                              const int* fill, const float* w2l,
                                              const int* batch, float* out, int nN, int nE, int nG) {
    __shared__ float bins[64];
    int t = threadIdx.x;
    if (t < 64) bins[t] = 0.f;
    __syncthreads();
    int i = blockIdx.x * 256 + t;
    if (i < nE) {
        int s = src[i], d = dst[i];
        float val = rsqrtf((float)(fill[s] + 1) * (float)(fill[d] + 1)) * z[s];
        int g = batch[d];
        if (g < 64) atomicAdd(&bins[g], val); else atomicAdd(&out[g], val);
    }
    if (i < nN) {
        float val = w2l[D] + z[i] / (float)(fill[i] + 1);
        int g = batch[i];
        if (g < 64) atomicAdd(&bins[g], val); else atomicAdd(&out[g], val);
    }
    __syncthreads();
    if (t < 64 && t < nG) {
        float v = bins[t];
        if (v != 0.f) atomicAdd(&out[t], v);
    }
}

extern "C" void kernel_launch(void* const* d_in, const int* in_sizes, int n_in,
                              void* d_out, int out_size, void* d_ws, size_t ws_size,
                              hipStream_t stream) {
    const float* x    = (const float*)d_in[0];
    const int*   ei   = (const int*)d_in[1];
    const int*   batch= (const int*)d_in[2];
    const float* W1   = (const float*)d_in[4];
    const float* b1   = (const float*)d_in[5];
    const float* W2   = (const float*)d_in[6];
    const float* b2   = (const float*)d_in[7];
    const float* Wlin = (const float*)d_in[8];
    const float* blin = (const float*)d_in[9];
    float* out = (float*)d_out;

    int nN = in_sizes[0] / D;      // 10000
    int nE = in_sizes[1] / 2;      // 160000
    int nG = out_size;             // 64
    const int* src = ei;
    const int* dst = ei + nE;

    char* p = (char*)d_ws;
    auto alloc = [&](size_t b) { char* r = p; p += (b + 255) & ~(size_t)255; return (void*)r; };
    int*   fz      = (int*)alloc((size_t)nN * 8);   // fill (nN ints) + z (nN floats) contiguous
    int*   fill    = fz;
    float* z       = (float*)(fz + nN);
    int*   csr_src = (int*)alloc((size_t)nN * CAP * 4);
    float* w2l     = (float*)alloc((size_t)(D + 1) * 4);
    unsigned short* h1b = (unsigned short*)alloc((size_t)nN * D * 2);

    hipMemsetAsync(fz, 0, (size_t)nN * 8, stream);   // zero fill + z in one node

    int nb = 316 + (nE + 255) / 256 + 129 + 1;       // gemm + scatter + w2l + out-init
    k_gemm_scatter<<<nb, 256, 0, stream>>>(x, W1, h1b, nN, src, dst, fill, csr_src, nE,
                                           W2, Wlin, b2, blin, w2l, out, nG);
    k_agg1<<<313 * 8, 256, 0, stream>>>(h1b, csr_src, fill, b1, w2l, z, nN);
    nb = (nE + 255) / 256;
    k_agg2<<<nb, 256, 0, stream>>>(z, src, dst, fill, w2l, batch, out, nN, nE, nG);
}

// Round 21
// 67.957 us; speedup vs baseline: 1.0233x; 1.0233x over previous
//
#include <hip/hip_runtime.h>
#include <stdint.h>

typedef __attribute__((ext_vector_type(8))) short s16x8;
typedef __attribute__((ext_vector_type(8))) unsigned short u16x8;
typedef __attribute__((ext_vector_type(4))) float f32x4;

#define D 512
#define BM 128
#define BK 64
#define CAP 96   // padded CSR row capacity; P(deg>=96) ~ 1e-40 for Binom(160000,1e-4)

__device__ __forceinline__ unsigned short f2bf(float f) {
    unsigned u = __float_as_uint(f);
    return (unsigned short)((u + 0x7FFFu + ((u >> 16) & 1u)) >> 16);
}
__device__ __forceinline__ float bf2f(unsigned short h) {
    return __uint_as_float(((unsigned)h) << 16);
}

// ---------------- prep: W1^T -> bf16 transpose (blocks 0..63), zero fill/z (64..103) ----------------
__global__ __launch_bounds__(256) void k_prep(const float* W1, int* fill, float* z,
                                              unsigned short* w1t, int nN) {
    int b = blockIdx.x, t = threadIdx.x;
    if (b < 64) {
        __shared__ float tile[64][65];
        int ti = b >> 3, tj = b & 7;          // ti: k-tile, tj: n-tile
#pragma unroll
        for (int p = 0; p < 4; ++p) {
            int r = p * 16 + (t >> 4);
            int c = (t & 15) * 4;
            float4 v = *(const float4*)(W1 + (size_t)(ti * 64 + r) * D + tj * 64 + c);
            tile[r][c] = v.x; tile[r][c + 1] = v.y; tile[r][c + 2] = v.z; tile[r][c + 3] = v.w;
        }
        __syncthreads();
        int c = t >> 2;                        // 0..63 (n within tile)
        int r0 = (t & 3) * 16;                 // 0,16,32,48 (k within tile)
        u16x8 o0, o1;
#pragma unroll
        for (int i = 0; i < 8; ++i) o0[i] = f2bf(tile[r0 + i][c]);
#pragma unroll
        for (int i = 0; i < 8; ++i) o1[i] = f2bf(tile[r0 + 8 + i][c]);
        unsigned short* wp = w1t + (size_t)(tj * 64 + c) * D + ti * 64 + r0;
        *(u16x8*)wp = o0;
        *(u16x8*)(wp + 8) = o1;
    } else {
        int i = (b - 64) * 256 + t;
        if (i < nN) { fill[i] = 0; z[i] = 0.f; }
    }
}

// ---------------- fused launch 2: GEMM (0..315, double-buffered pipeline) +
//                  scatter (316..940) + w2l (941..1069) + out-init (1070) ----------------
__global__ __launch_bounds__(256) void k_gemm_scatter(const float* X, const unsigned short* BT,
                                                      unsigned short* C, int Mreal,
                                                      const int* src, const int* dst,
                                                      int* fill, int* csr_src, int nE,
                                                      const float* W2, const float* Wlin,
                                                      const float* b2, const float* blin,
                                                      float* w2l, float* out, int nG) {
    __shared__ __align__(16) unsigned short smem[4 * BM * BK];   // As[2] + Bs[2] = 64 KB
    int b = blockIdx.x;
    int t = threadIdx.x;
    if (b >= 316) {
        int br = b - 316;
        if (br < 625) {                    // ---- scatter role: count + claim slot ----
            int e = br * 256 + t;
            if (e < nE) {
                int s = src[e], d = dst[e];
                int pos = atomicAdd(&fill[d], 1);
                if (pos < CAP) csr_src[(size_t)d * CAP + pos] = s;
            }
        } else if (br < 754) {             // ---- w2l role: one wave per row ----
            int i = (br - 625) * 4 + (t >> 6);
            int l = t & 63;
            if (i < D + 1) {
                const float* row = (i < D) ? (W2 + (size_t)i * D) : b2;
                float4 a0 = *(const float4*)(row + l * 8);
                float4 a1 = *(const float4*)(row + l * 8 + 4);
                float4 c0 = *(const float4*)(Wlin + l * 8);
                float4 c1 = *(const float4*)(Wlin + l * 8 + 4);
                float p = a0.x * c0.x + a0.y * c0.y + a0.z * c0.z + a0.w * c0.w
                        + a1.x * c1.x + a1.y * c1.y + a1.z * c1.z + a1.w * c1.w;
#pragma unroll
                for (int o = 32; o > 0; o >>= 1) p += __shfl_xor(p, o);
                if (l == 0) w2l[i] = p;
            }
        } else {                           // ---- out init ----
            if (t < nG) out[t] = blin[0];
        }
        return;
    }
    // ---- GEMM role: double-buffered; 1 barrier/K-step; loads overlap MFMA ----
    int tn0 = (b & 3) * BM, tm0 = (b >> 2) * BM;
    int lane = t & 63, wave = t >> 6;
    int wr = wave >> 1, wc = wave & 1;
    f32x4 acc[4][4] = {};
    int r15 = lane & 15;
    int khalf = lane >> 4;

    // per-thread staging geometry (A: 4 16B-groups; B via GLL: 4 wave-calls)
    int a_row[4], a_kg[4];
    const float* a_gp_base[4];
#pragma unroll
    for (int i = 0; i < 4; ++i) {
        int idx = t + 256 * i;
        a_row[i] = idx >> 3; a_kg[i] = idx & 7;
        int grow = tm0 + a_row[i]; if (grow >= Mreal) grow = Mreal - 1;
        a_gp_base[i] = X + (size_t)grow * D + a_kg[i] * 8;
    }

    auto issue_B = [&](unsigned short* Bsbuf, int k0) {
        int rb0 = wave * 8;
#pragma unroll
        for (int c = 0; c < 4; ++c) {
            int rbase = c * 32 + rb0;
            int row = rbase + (lane >> 3);
            int kg = (lane & 7) ^ (row & 7);
            const unsigned short* gsrc = BT + (size_t)(tn0 + row) * D + k0 + kg * 8;
            __builtin_amdgcn_global_load_lds(
                (const __attribute__((address_space(1))) unsigned int*)gsrc,
                (__attribute__((address_space(3))) unsigned int*)(Bsbuf + rbase * BK),
                16, 0, 0);
        }
    };

    float4 af0[4], af1[4];
    auto load_A = [&](int k0) {
#pragma unroll
        for (int i = 0; i < 4; ++i) {
            const float* gp = a_gp_base[i] + k0;
            af0[i] = *(const float4*)gp;
            af1[i] = *(const float4*)(gp + 4);
        }
    };
    auto write_A = [&](unsigned short* Asbuf) {
#pragma unroll
        for (int i = 0; i < 4; ++i) {
            u16x8 o;
            o[0] = f2bf(af0[i].x); o[1] = f2bf(af0[i].y); o[2] = f2bf(af0[i].z); o[3] = f2bf(af0[i].w);
            o[4] = f2bf(af1[i].x); o[5] = f2bf(af1[i].y); o[6] = f2bf(af1[i].z); o[7] = f2bf(af1[i].w);
            *(u16x8*)&Asbuf[a_row[i] * BK + (a_kg[i] ^ (a_row[i] & 7)) * 8] = o;
        }
    };

    // prologue: fill buffer 0
    issue_B(smem + 2 * BM * BK, 0);
    load_A(0);
    write_A(smem);
    __syncthreads();

    int cur = 0;
    for (int k0 = 0; k0 < D; k0 += BK) {
        unsigned short* Asc = smem + cur * BM * BK;
        unsigned short* Bsc = smem + (2 + cur) * BM * BK;
        if (k0 + BK < D) {                 // prefetch next K-step (overlaps MFMA below)
            issue_B(smem + (2 + (cur ^ 1)) * BM * BK, k0 + BK);
            load_A(k0 + BK);
        }
#pragma unroll
        for (int ks = 0; ks < 2; ++ks) {
            int g = ks * 4 + khalf;
            s16x8 a[4], bb[4];
#pragma unroll
            for (int m = 0; m < 4; ++m) {
                int row = wr * 64 + m * 16 + r15;
                a[m] = *(const s16x8*)&Asc[row * BK + (g ^ (row & 7)) * 8];
            }
#pragma unroll
            for (int n = 0; n < 4; ++n) {
                int row = wc * 64 + n * 16 + r15;
                bb[n] = *(const s16x8*)&Bsc[row * BK + (g ^ (row & 7)) * 8];
            }
#pragma unroll
            for (int m = 0; m < 4; ++m)
#pragma unroll
                for (int n = 0; n < 4; ++n)
                    acc[m][n] = __builtin_amdgcn_mfma_f32_16x16x32_bf16(a[m], bb[n], acc[m][n], 0, 0, 0);
        }
        if (k0 + BK < D) write_A(smem + (cur ^ 1) * BM * BK);
        __syncthreads();                   // drains vmcnt (GLL) + makes As[nxt] visible
        cur ^= 1;
    }

    // ---- epilogue: repack C-tile in LDS (loop ended with barrier), coalesced 16B stores ----
    int cr = (lane >> 4) * 4;
    int cc = lane & 15;
#pragma unroll
    for (int m = 0; m < 4; ++m)
#pragma unroll
        for (int n = 0; n < 4; ++n)
#pragma unroll
            for (int r = 0; r < 4; ++r)
                smem[(wr * 64 + m * 16 + cr + r) * 132 + wc * 64 + n * 16 + cc] = f2bf(acc[m][n][r]);
    __syncthreads();
#pragma unroll
    for (int it = 0; it < 8; ++it) {
        int row = it * 16 + (t >> 4);       // 16 rows per pass, 16 lanes each
        int c8 = (t & 15) * 8;
        int grow = tm0 + row;
        if (grow < Mreal) {
            u16x8 vv = *(const u16x8*)&smem[row * 132 + c8];
            *(u16x8*)&C[(size_t)grow * D + tn0 + c8] = vv;
        }
    }
}

// ---------------- layer1 aggregate, feature-sliced + XCD-pinned, padded CSR (r13 exact) ----------------
__global__ __launch_bounds__(256) void k_agg1(const unsigned short* h1b, const int* csr_src,
                                              const int* fill, const float* b1,
                                              const float* w2l, float* z, int nN) {
    int bid = blockIdx.x;
    int xcd = bid & 7;
    int slice = xcd >> 1;
    int chunk = (bid >> 3) * 2 + (xcd & 1);   // node chunk of 16
    int t = threadIdx.x;
    int g = t >> 4;                 // group 0..15 in block
    int l = t & 15;                 // lane in group
    int v = chunk * 16 + g;
    if (v >= nN) return;
    int f0 = (slice << 7) + l * 8;

    float acc[8];
    float4 ba = *(const float4*)(b1 + f0);
    float4 bb = *(const float4*)(b1 + f0 + 4);
    acc[0] = ba.x; acc[1] = ba.y; acc[2] = ba.z; acc[3] = ba.w;
    acc[4] = bb.x; acc[5] = bb.y; acc[6] = bb.z; acc[7] = bb.w;

    int deg = fill[v];
    float degv1 = (float)(deg + 1);
    float wself = 1.0f / degv1;
    u16x8 hv = *(const u16x8*)(h1b + (size_t)v * D + f0);
#pragma unroll
    for (int j = 0; j < 8; ++j) acc[j] += wself * bf2f(hv[j]);

    const int* row = csr_src + (size_t)v * CAP;
    int sb = (g & 3) << 4;          // group's base lane within the wave
    for (int eb = 0; eb < deg; eb += 16) {
        int n = deg - eb; if (n > 16) n = 16;
        int myi = 0; float myw = 0.f;
        if (l < n) {
            myi = row[eb + l];
            myw = rsqrtf((float)(fill[myi] + 1) * degv1);
        }
        int j = 0;
        for (; j + 4 <= n; j += 4) {
            int s0 = __shfl(myi, sb + j),     s1 = __shfl(myi, sb + j + 1);
            int s2 = __shfl(myi, sb + j + 2), s3 = __shfl(myi, sb + j + 3);
            float w0 = __shfl(myw, sb + j),     w1 = __shfl(myw, sb + j + 1);
            float w2 = __shfl(myw, sb + j + 2), w3 = __shfl(myw, sb + j + 3);
            u16x8 h0 = *(const u16x8*)(h1b + (size_t)s0 * D + f0);
            u16x8 h1 = *(const u16x8*)(h1b + (size_t)s1 * D + f0);
            u16x8 h2 = *(const u16x8*)(h1b + (size_t)s2 * D + f0);
            u16x8 h3 = *(const u16x8*)(h1b + (size_t)s3 * D + f0);
#pragma unroll
            for (int q = 0; q < 8; ++q) acc[q] += w0 * bf2f(h0[q]);
#pragma unroll
            for (int q = 0; q < 8; ++q) acc[q] += w1 * bf2f(h1[q]);
#pragma unroll
            for (int q = 0; q < 8; ++q) acc[q] += w2 * bf2f(h2[q]);
#pragma unroll
            for (int q = 0; q < 8; ++q) acc[q] += w3 * bf2f(h3[q]);
        }
        for (; j < n; ++j) {
            int s = __shfl(myi, sb + j);
            float w = __shfl(myw, sb + j);
            u16x8 hs = *(const u16x8*)(h1b + (size_t)s * D + f0);
#pragma unroll
            for (int q = 0; q < 8; ++q) acc[q] += w * bf2f(hs[q]);
        }
    }

    float4 wa = *(const float4*)(w2l + f0);
    float4 wb = *(const float4*)(w2l + f0 + 4);
    float wv[8] = {wa.x, wa.y, wa.z, wa.w, wb.x, wb.y, wb.z, wb.w};
    float p = 0.f;
#pragma unroll
    for (int j = 0; j < 8; ++j) p += fmaxf(acc[j], 0.f) * wv[j];
    p += __shfl_xor(p, 8);
    p += __shfl_xor(p, 4);
    p += __shfl_xor(p, 2);
    p += __shfl_xor(p, 1);
    if (l == 0) atomicAdd(&z[v], p);
}

// ---------------- layer2 scalar aggregate + pool (edge-parallel, LDS bins) ----------------
__global__ __launch_bounds__(256) void k_agg2(const float* z, const int* src, const int* dst,
                                              const int* fill, const float* w2l,
                                              const int* batch, float* out, int nN, int nE, int nG) {
    __shared__ float bins[64];
    int t = threadIdx.x;
    if (t < 64) bins[t] = 0.f;
    __syncthreads();
    int i = blockIdx.x * 256 + t;
    if (i < nE) {
        int s = src[i], d = dst[i];
        float val = rsqrtf((float)(fill[s] + 1) * (float)(fill[d] + 1)) * z[s];
        int g = batch[d];
        if (g < 64) atomicAdd(&bins[g], val); else atomicAdd(&out[g], val);
    }
    if (i < nN) {
        float val = w2l[D] + z[i] / (float)(fill[i] + 1);
        int g = batch[i];
        if (g < 64) atomicAdd(&bins[g], val); else atomicAdd(&out[g], val);
    }
    __syncthreads();
    if (t < 64 && t < nG) {
        float v = bins[t];
        if (v != 0.f) atomicAdd(&out[t], v);
    }
}

extern "C" void kernel_launch(void* const* d_in, const int* in_sizes, int n_in,
                              void* d_out, int out_size, void* d_ws, size_t ws_size,
                              hipStream_t stream) {
    const float* x    = (const float*)d_in[0];
    const int*   ei   = (const int*)d_in[1];
    const int*   batch= (const int*)d_in[2];
    const float* W1   = (const float*)d_in[4];
    const float* b1   = (const float*)d_in[5];
    const float* W2   = (const float*)d_in[6];
    const float* b2   = (const float*)d_in[7];
    const float* Wlin = (const float*)d_in[8];
    const float* blin = (const float*)d_in[9];
    float* out = (float*)d_out;

    int nN = in_sizes[0] / D;      // 10000
    int nE = in_sizes[1] / 2;      // 160000
    int nG = out_size;             // 64
    const int* src = ei;
    const int* dst = ei + nE;

    char* p = (char*)d_ws;
    auto alloc = [&](size_t b) { char* r = p; p += (b + 255) & ~(size_t)255; return (void*)r; };
    int*   fill    = (int*)alloc((size_t)nN * 4);
    int*   csr_src = (int*)alloc((size_t)nN * CAP * 4);
    float* z       = (float*)alloc((size_t)nN * 4);
    float* w2l     = (float*)alloc((size_t)(D + 1) * 4);
    unsigned short* w1t = (unsigned short*)alloc((size_t)D * D * 2);
    unsigned short* h1b = (unsigned short*)alloc((size_t)nN * D * 2);

    k_prep<<<104, 256, 0, stream>>>(W1, fill, z, w1t, nN);
    int nb = 316 + (nE + 255) / 256 + 129 + 1;     // gemm + scatter + w2l + out-init
    k_gemm_scatter<<<nb, 256, 0, stream>>>(x, w1t, h1b, nN, src, dst, fill, csr_src, nE,
                                           W2, Wlin, b2, blin, w2l, out, nG);
    k_agg1<<<313 * 8, 256, 0, stream>>>(h1b, csr_src, fill, b1, w2l, z, nN);
    nb = (nE + 255) / 256;
    k_agg2<<<nb, 256, 0, stream>>>(z, src, dst, fill, w2l, batch, out, nN, nE, nG);
}